// Round 1
// baseline (281.506 us; speedup 1.0000x reference)
//
#include <hip/hip_runtime.h>
#include <math.h>

// CovidModel: M[t][s] = sum_j A_full[J+t-1-j][s] * rho[s] * pi[j][s]
// A recursion replaced by closed form:
//   A[t][s] = A0[s] * exp2f(invT[s]*L[t] + (t+1)*log2(delta[s]))
//   L[t] = prefix sum of log2(r_t)  (sample-independent, precomputed into d_ws)
// This removes the sequential scan -> tile T across blocks for occupancy.

#define T_DAYS 1024
#define J_WIN  32
#define DT     128   // days per block chunk (multiple of 32)

// Kernel 1: L[t] = inclusive prefix sum of log2(r_t[t]); one block, 1024 threads.
__global__ void prefix_log_kernel(const float* __restrict__ r_t,
                                  float* __restrict__ L) {
    __shared__ float buf[T_DAYS];
    const int i = threadIdx.x;
    buf[i] = __log2f(r_t[i]);
    __syncthreads();
    // Hillis-Steele inclusive scan
    for (int off = 1; off < T_DAYS; off <<= 1) {
        float add = (i >= off) ? buf[i - off] : 0.0f;
        __syncthreads();
        buf[i] += add;
        __syncthreads();
    }
    L[i] = buf[i];
}

// Kernel 2: main forecast. One sample per lane, DT days per block (blockIdx.y).
__global__ __launch_bounds__(256, 4)
void covid_kernel(const float* __restrict__ warmup_A,
                  const float* __restrict__ delta_p,
                  const float* __restrict__ T_serial,
                  const float* __restrict__ rho_p,
                  const float* __restrict__ pi_M,
                  const float* __restrict__ L,
                  float* __restrict__ out,
                  int S) {
    const int s  = blockIdx.x * 256 + threadIdx.x;
    const int t0 = blockIdx.y * DT;   // multiple of 32

    // Stage the L window this block needs: days [t0-32, t0+DT-1]
    __shared__ float Lsh[DT + J_WIN];
    for (int k = threadIdx.x; k < DT + J_WIN; k += 256) {
        int d = t0 - J_WIN + k;
        Lsh[k] = (d >= 0) ? L[d] : 0.0f;
    }
    __syncthreads();
    if (s >= S) return;

    const float invT = 1.0f / T_serial[s];
    const float dlt  = delta_p[s];
    const float ld   = __log2f(dlt);
    const float rho  = rho_p[s];
    const float A0   = warmup_A[(J_WIN - 1) * S + s];
    const float t0f  = (float)t0;

    // Folded weights: w[j] = rho * pi[j][s]  (registers)
    float w[J_WIN];
#pragma unroll
    for (int j = 0; j < J_WIN; ++j) w[j] = rho * pi_M[j * S + s];

    // Ring buffer holds A(d) for the 32 most recent days; A(d) lives at
    // ring[d & 31] (d>=0), warmup day d<0 lives at ring[d+32].
    float ring[J_WIN];
    if (t0 == 0) {
#pragma unroll
        for (int k = 0; k < J_WIN; ++k) ring[k] = warmup_A[k * S + s];
    } else {
#pragma unroll
        for (int k = 0; k < J_WIN; ++k) {
            // day d = t0 - 32 + k  (>= 0); position d & 31 == k
            float arg = fmaf(invT, Lsh[k], (t0f - (float)J_WIN + (float)(k + 1)) * ld);
            ring[k] = A0 * exp2f(arg);
        }
    }

    for (int tt = 0; tt < DT; tt += J_WIN) {
#pragma unroll
        for (int u = 0; u < J_WIN; ++u) {
            const int t = t0 + tt + u;
            // M[t] = sum_j w[j] * A(t-1-j); ring index (u-1-j)&31 is constant
            float m0 = 0.0f, m1 = 0.0f, m2 = 0.0f, m3 = 0.0f;
#pragma unroll
            for (int j = 0; j < J_WIN; j += 4) {
                m0 = fmaf(w[j + 0], ring[(u - 1 - j) & 31], m0);
                m1 = fmaf(w[j + 1], ring[(u - 2 - j) & 31], m1);
                m2 = fmaf(w[j + 2], ring[(u - 3 - j) & 31], m2);
                m3 = fmaf(w[j + 3], ring[(u - 4 - j) & 31], m3);
            }
            out[(size_t)t * S + s] = (m0 + m1) + (m2 + m3);
            // A(t) closed form; overwrite oldest (day t-32) at ring[u]
            float arg = fmaf(invT, Lsh[tt + u + J_WIN],
                             (t0f + (float)(tt + u + 1)) * ld);
            ring[u] = A0 * exp2f(arg);
        }
    }
}

extern "C" void kernel_launch(void* const* d_in, const int* in_sizes, int n_in,
                              void* d_out, int out_size, void* d_ws, size_t ws_size,
                              hipStream_t stream) {
    const float* r_t      = (const float*)d_in[0];
    const float* warmup_A = (const float*)d_in[1];
    const float* delta    = (const float*)d_in[2];
    const float* T_serial = (const float*)d_in[3];
    const float* rho_M    = (const float*)d_in[4];
    const float* pi_M     = (const float*)d_in[5];
    float* out = (float*)d_out;
    float* L   = (float*)d_ws;          // T_DAYS floats of scratch
    const int S = in_sizes[2];          // 50000

    prefix_log_kernel<<<1, T_DAYS, 0, stream>>>(r_t, L);

    dim3 grid((S + 255) / 256, T_DAYS / DT);
    covid_kernel<<<grid, 256, 0, stream>>>(warmup_A, delta, T_serial, rho_M,
                                           pi_M, L, out, S);
}

// Round 2
// 254.201 us; speedup vs baseline: 1.1074x; 1.1074x over previous
//
#include <hip/hip_runtime.h>
#include <math.h>

// CovidModel: M[t][s] = sum_j A_full[J+t-1-j][s] * rho[s] * pi[j][s]
// A recursion replaced by closed form (removes the sequential scan):
//   A[d][s] = A0[s] * exp2(invT[s]*L[d] + (d+1)*log2(delta[s]))
//   L[d] = prefix sum of log2(r_t)  (sample-independent, in d_ws)
// DT=32: one fully-unrolled day loop (~11 KB code, fits 32 KB I$ — the
// DT=128 version's ~40 KB+ unrolled body thrashed instruction fetch).

#define T_DAYS 1024
#define J_WIN  32
#define DT     32    // days per block chunk == J_WIN (ring does one full turn)

// Kernel 1: L[t] = inclusive prefix sum of log2(r_t[t]); one block.
__global__ void prefix_log_kernel(const float* __restrict__ r_t,
                                  float* __restrict__ L) {
    __shared__ float buf[T_DAYS];
    const int i = threadIdx.x;
    buf[i] = __log2f(r_t[i]);
    __syncthreads();
    for (int off = 1; off < T_DAYS; off <<= 1) {
        float add = (i >= off) ? buf[i - off] : 0.0f;
        __syncthreads();
        buf[i] += add;
        __syncthreads();
    }
    L[i] = buf[i];
}

// Kernel 2: main forecast. One sample per lane, 32 days per block.
__global__ __launch_bounds__(256, 4)
void covid_kernel(const float* __restrict__ warmup_A,
                  const float* __restrict__ delta_p,
                  const float* __restrict__ T_serial,
                  const float* __restrict__ rho_p,
                  const float* __restrict__ pi_M,
                  const float* __restrict__ L,
                  float* __restrict__ out,
                  int S) {
    const int s  = blockIdx.x * 256 + threadIdx.x;
    const int t0 = blockIdx.y * DT;   // multiple of 32

    // L window this block needs: days [t0-32, t0+32)
    __shared__ float Lsh[2 * J_WIN];
    for (int k = threadIdx.x; k < 2 * J_WIN; k += 256) {
        int d = t0 - J_WIN + k;
        Lsh[k] = (d >= 0) ? L[d] : 0.0f;
    }
    __syncthreads();
    if (s >= S) return;

    const float invT = 1.0f / T_serial[s];
    const float dlt  = delta_p[s];
    const float ld   = __log2f(dlt);
    const float rho  = rho_p[s];
    const float A0   = warmup_A[(J_WIN - 1) * S + s];
    const float t0f  = (float)t0;

    // Folded weights w[j] = rho * pi[j][s] (registers, compile-time indexed)
    float w[J_WIN];
#pragma unroll
    for (int j = 0; j < J_WIN; ++j) w[j] = rho * pi_M[j * S + s];

    // Ring: A(day d) lives at ring[d mod 32] (warmup day d<0 at d+32).
    // t0 is a multiple of 32, so init day t0-32+k sits at slot k.
    float ring[J_WIN];
    if (t0 == 0) {
#pragma unroll
        for (int k = 0; k < J_WIN; ++k) ring[k] = warmup_A[k * S + s];
    } else {
#pragma unroll
        for (int k = 0; k < J_WIN; ++k) {
            float arg = fmaf(invT, Lsh[k],
                             (t0f - (float)J_WIN + (float)(k + 1)) * ld);
            ring[k] = A0 * __builtin_amdgcn_exp2f(arg);
        }
    }

    float* op = out + (size_t)t0 * S + s;
#pragma unroll
    for (int u = 0; u < DT; ++u) {
        // M[t0+u] = sum_j w[j] * A(t0+u-1-j); ring slot (u-1-j)&31 is a
        // compile-time constant after unrolling.
        float m0 = 0.0f, m1 = 0.0f, m2 = 0.0f, m3 = 0.0f;
#pragma unroll
        for (int j = 0; j < J_WIN; j += 4) {
            m0 = fmaf(w[j + 0], ring[(u - 1 - j) & 31], m0);
            m1 = fmaf(w[j + 1], ring[(u - 2 - j) & 31], m1);
            m2 = fmaf(w[j + 2], ring[(u - 3 - j) & 31], m2);
            m3 = fmaf(w[j + 3], ring[(u - 4 - j) & 31], m3);
        }
        op[(size_t)u * S] = (m0 + m1) + (m2 + m3);
        // A(t0+u) closed form; overwrites oldest slot (day t0+u-32).
        float arg = fmaf(invT, Lsh[J_WIN + u], (t0f + (float)(u + 1)) * ld);
        ring[u] = A0 * __builtin_amdgcn_exp2f(arg);
    }
}

extern "C" void kernel_launch(void* const* d_in, const int* in_sizes, int n_in,
                              void* d_out, int out_size, void* d_ws, size_t ws_size,
                              hipStream_t stream) {
    const float* r_t      = (const float*)d_in[0];
    const float* warmup_A = (const float*)d_in[1];
    const float* delta    = (const float*)d_in[2];
    const float* T_serial = (const float*)d_in[3];
    const float* rho_M    = (const float*)d_in[4];
    const float* pi_M     = (const float*)d_in[5];
    float* out = (float*)d_out;
    float* L   = (float*)d_ws;          // T_DAYS floats of scratch
    const int S = in_sizes[2];          // 50000

    prefix_log_kernel<<<1, T_DAYS, 0, stream>>>(r_t, L);

    dim3 grid((S + 255) / 256, T_DAYS / DT);
    covid_kernel<<<grid, 256, 0, stream>>>(warmup_A, delta, T_serial, rho_M,
                                           pi_M, L, out, S);
}